// Round 8
// baseline (12139.883 us; speedup 1.0000x reference)
//
#include <hip/hip_runtime.h>

// NewGRU: B=64, T=2048, D=256, U=256
// R7: real path = VERBATIM R4 (3561us scan, verified correct).  Plus three
// ablation probes (outputs -> tail of d_ws, healed by proj each launch):
//   probe_noread : no h/r ds_read_b128 (MFMA fed from register)
//   probe_noring : no DMA ring / vmcnt (A' from registers)
//   probe_skel   : both removed (skeleton floor)

#define TT 2048
#define DD 256

typedef __attribute__((ext_vector_type(8))) short short8;          // 8 x bf16 bits
typedef __attribute__((ext_vector_type(4))) unsigned short us4;    // 4 x bf16 bits
typedef __attribute__((ext_vector_type(2))) unsigned int uint2v;   // 8B store
typedef __attribute__((ext_vector_type(4))) float f32x4;

__device__ __forceinline__ unsigned short f2bf(float f) {          // RTN f32->bf16
  unsigned u = __float_as_uint(f);
  return (unsigned short)((u + 0x7FFFu + ((u >> 16) & 1u)) >> 16);
}
__device__ __forceinline__ float bf2f(unsigned short s) {
  return __uint_as_float(((unsigned)s) << 16);
}
__device__ __forceinline__ unsigned pk2(float lo, float hi) {      // 2xbf16 pack
  unsigned a = __float_as_uint(lo) + 0x8000u;
  unsigned b = __float_as_uint(hi) + 0x8000u;
  return (b & 0xFFFF0000u) | (a >> 16);
}
__device__ __forceinline__ float sigmoid_f(float x) {
  return __builtin_amdgcn_rcpf(1.f + __builtin_amdgcn_exp2f(x * -1.44269504f));
}
__device__ __forceinline__ float tanh_f(float x) {
  return 1.f - 2.f * __builtin_amdgcn_rcpf(1.f + __builtin_amdgcn_exp2f(x * 2.88539008f));
}
__device__ __forceinline__ f32x4 mfma16(short8 a, short8 b, f32x4 c) {
  return __builtin_amdgcn_mfma_f32_16x16x32_bf16(a, b, c, 0, 0, 0);
}
__device__ __forceinline__ void load_lds16(const void* gp, void* lp) {
  __builtin_amdgcn_global_load_lds((__attribute__((address_space(1))) void*)(gp),
                                   (__attribute__((address_space(3))) void*)(lp),
                                   16, 0, 0);
}
// XOR swizzle used only by proj_kernel's x tile (verified R1).
__device__ __forceinline__ unsigned swz(unsigned row, unsigned byteInRow) {
  return row * 512u + (byteInRow ^ ((row & 7u) << 4));
}

// ---------------------------------------------------------------------------
// proj_kernel: VERBATIM R4 (verified).
// ---------------------------------------------------------------------------
__global__ __launch_bounds__(512) void proj_kernel(
    const float* __restrict__ x,
    const float* __restrict__ Wxu, const float* __restrict__ Wxr,
    const float* __restrict__ Wxo,
    const float* __restrict__ bu, const float* __restrict__ br,
    const float* __restrict__ bo,
    unsigned short* __restrict__ Ap)
{
  __shared__ alignas(16) unsigned short x_lds[16 * 256];

  const int tid = threadIdx.x;
  const int w = tid >> 6, l = tid & 63;
  const int q = l >> 4, b16 = l & 15;
  const int bblk = blockIdx.x & 3;
  const int tc = blockIdx.x >> 2;
  const int b0 = bblk * 16;

  short8 wx[6][8];
  f32x4 bbv[6];
#pragma unroll
  for (int n = 0; n < 6; ++n) {
    int ntg = w * 6 + n;
    const float* Wg = (ntg < 16) ? Wxu : (ntg < 32) ? Wxr : Wxo;
    const float* bg = (ntg < 16) ? bu : (ntg < 32) ? br : bo;
    int ct = ntg & 15;
    int col = ct * 16 + b16;
    int c0 = ct * 16 + q * 4;
    bbv[n] = (f32x4){bg[c0], bg[c0 + 1], bg[c0 + 2], bg[c0 + 3]};
#pragma unroll
    for (int kt = 0; kt < 8; ++kt) {
      int k0 = kt * 32 + q * 8;
      short8 f;
#pragma unroll
      for (int j = 0; j < 8; ++j) f[j] = (short)f2bf(Wg[(k0 + j) * 256 + col]);
      wx[n][kt] = f;
    }
  }

  for (int it = 0; it < 8; ++it) {
    const int t = tc * 8 + it;
    {
      int row = tid >> 5;
      int part = tid & 31;
      const float* src = x + (((size_t)(b0 + row) * TT + t) * DD) + part * 8;
      float4 f0 = *(const float4*)(src);
      float4 f1 = *(const float4*)(src + 4);
      us4 s0 = { f2bf(f0.x), f2bf(f0.y), f2bf(f0.z), f2bf(f0.w) };
      us4 s1 = { f2bf(f1.x), f2bf(f1.y), f2bf(f1.z), f2bf(f1.w) };
      unsigned base = swz((unsigned)row, (unsigned)(part * 16));
      *(us4*)((char*)x_lds + base) = s0;
      *(us4*)((char*)x_lds + base + 8) = s1;
    }
    __syncthreads();

    f32x4 acc[6];
#pragma unroll
    for (int n = 0; n < 6; ++n) acc[n] = bbv[n];
#pragma unroll
    for (int kt = 0; kt < 8; ++kt) {
      short8 xa = *(const short8*)((const char*)x_lds + swz(b16, kt * 64 + q * 16));
#pragma unroll
      for (int n = 0; n < 6; ++n) acc[n] = mfma16(wx[n][kt], xa, acc[n]);
    }
    __syncthreads();

#pragma unroll
    for (int n = 0; n < 6; ++n) {
      int ntg = w * 6 + n;
      int g = ntg >> 4, ct = ntg & 15;
      us4 st = { f2bf(acc[n][0]), f2bf(acc[n][1]), f2bf(acc[n][2]), f2bf(acc[n][3]) };
      size_t base = (((size_t)t * 3 + g) * 4 + bblk) * 4096
                    + (ct >> 1) * 512 + l * 8 + (ct & 1) * 4;
      *(us4*)(Ap + base) = st;
    }
  }
}

// ---------------------------------------------------------------------------
// Shared scan body. NOREAD: replace h/r fragment ds_reads with a register.
// NORING: remove DMA ring, vmcnt waits, ring reads (A' from registers).
// <0,0> is the exact R4 scan (real path).
// ---------------------------------------------------------------------------
#define RING_SLOT 24576
#define HOFF 98304
#define ROFF 107008

template<int NOREAD, int NORING>
__device__ __forceinline__ void scan_body(
    const float* __restrict__ Whu, const float* __restrict__ Whr,
    const float* __restrict__ Wro,
    const unsigned short* __restrict__ Ap,
    float* __restrict__ outp)
{
  __shared__ alignas(16) char lds8[115712];

  const int tid = threadIdx.x;
  const int w = tid >> 6, l = tid & 63;
  const int q = l >> 4, b16 = l & 15;
  const int bblk = blockIdx.x;
  const int cw = w * 32;

  short8 wbu[2][8], wbr[2][8], wbo[2][8];
#pragma unroll
  for (int n = 0; n < 2; ++n) {
    const int col = cw + n * 16 + b16;
#pragma unroll
    for (int kt = 0; kt < 8; ++kt) {
      const int k0 = kt * 32 + q * 8;
      short8 fu, fr, fo;
#pragma unroll
      for (int j = 0; j < 8; ++j) {
        fu[j] = (short)f2bf(Whu[(k0 + j) * 256 + col]);
        fr[j] = (short)f2bf(Whr[(k0 + j) * 256 + col]);
        fo[j] = (short)f2bf(Wro[(k0 + j) * 256 + col]);
      }
      wbu[n][kt] = fu; wbr[n][kt] = fr; wbo[n][kt] = fo;
    }
  }

  const unsigned rowb = (unsigned)(b16 * 544);
  const char* hrd = lds8 + HOFF + rowb + q * 16;
  const char* rrd = lds8 + ROFF + rowb + q * 16;
  char* hwr0 = lds8 + HOFF + rowb + (cw + q * 4) * 2;
  char* rwr0 = lds8 + ROFF + rowb + (cw + q * 4) * 2;
  const char* ringr = lds8 + w * 1024 + l * 16;

  const unsigned short* apl = Ap + (size_t)bblk * 4096 + w * 512 + l * 8;

  for (int i = tid; i < 8704 / 4; i += 512) *(int*)(lds8 + HOFF + i * 4) = 0;

  float hm0 = 0, hm1 = 0, hm2 = 0, hm3 = 0, hm4 = 0, hm5 = 0, hm6 = 0, hm7 = 0;

  if constexpr (!NORING) {
#pragma unroll
    for (int t0 = 0; t0 < 3; ++t0) {
      const unsigned short* s = apl + (size_t)t0 * 49152u;
      char* d = lds8 + (t0 & 3) * RING_SLOT + w * 1024;
      load_lds16(s,         d);
      load_lds16(s + 16384, d + 8192);
      load_lds16(s + 32768, d + 16384);
    }
  }
  __syncthreads();

  // probe-only register substitutes (read once; zeros / real A'(0))
  short8 hreg = *(const short8*)(hrd);
  short8 caU = *(const short8*)(apl);
  short8 caR = *(const short8*)(apl + 16384);
  short8 caO = *(const short8*)(apl + 32768);

#define STEP_BODY(T)                                                             \
  {                                                                              \
    if constexpr (!NORING) {                                                     \
      asm volatile("s_waitcnt vmcnt(6)" ::: "memory");                           \
      int tp = (T) + 3; if (tp > TT - 1) tp = TT - 1;                            \
      const unsigned short* s = apl + (size_t)tp * 49152u;                       \
      char* d = lds8 + (tp & 3) * RING_SLOT + w * 1024;                          \
      load_lds16(s,         d);                                                  \
      load_lds16(s + 16384, d + 8192);                                           \
      load_lds16(s + 32768, d + 16384);                                          \
    }                                                                            \
    short8 aU, aR, aO;                                                           \
    if constexpr (!NORING) {                                                     \
      const char* rp = ringr + ((T) & 3) * RING_SLOT;                            \
      aU = *(const short8*)(rp);                                                 \
      aR = *(const short8*)(rp + 8192);                                          \
      aO = *(const short8*)(rp + 16384);                                         \
    } else { aU = caU; aR = caR; aO = caO; }                                     \
    f32x4 accu0 = (f32x4){bf2f((unsigned short)aU[0]), bf2f((unsigned short)aU[1]), \
                          bf2f((unsigned short)aU[2]), bf2f((unsigned short)aU[3])}; \
    f32x4 accu1 = (f32x4){bf2f((unsigned short)aU[4]), bf2f((unsigned short)aU[5]), \
                          bf2f((unsigned short)aU[6]), bf2f((unsigned short)aU[7])}; \
    f32x4 accr0 = (f32x4){bf2f((unsigned short)aR[0]), bf2f((unsigned short)aR[1]), \
                          bf2f((unsigned short)aR[2]), bf2f((unsigned short)aR[3])}; \
    f32x4 accr1 = (f32x4){bf2f((unsigned short)aR[4]), bf2f((unsigned short)aR[5]), \
                          bf2f((unsigned short)aR[6]), bf2f((unsigned short)aR[7])}; \
    _Pragma("unroll")                                                            \
    for (int kt = 0; kt < 8; ++kt) {                                             \
      short8 ha = NOREAD ? hreg : *(const short8*)(hrd + kt * 64);               \
      accr0 = mfma16(wbr[0][kt], ha, accr0);                                     \
      accr1 = mfma16(wbr[1][kt], ha, accr1);                                     \
      accu0 = mfma16(wbu[0][kt], ha, accu0);                                     \
      accu1 = mfma16(wbu[1][kt], ha, accu1);                                     \
    }                                                                            \
    {                                                                            \
      float ra0 = sigmoid_f(accr0[0]), ra1 = sigmoid_f(accr0[1]);                \
      float ra2 = sigmoid_f(accr0[2]), ra3 = sigmoid_f(accr0[3]);                \
      float rb0 = sigmoid_f(accr1[0]), rb1 = sigmoid_f(accr1[1]);                \
      float rb2 = sigmoid_f(accr1[2]), rb3 = sigmoid_f(accr1[3]);                \
      *(uint2v*)(rwr0)      = (uint2v){pk2(ra0, ra1), pk2(ra2, ra3)};            \
      *(uint2v*)(rwr0 + 32) = (uint2v){pk2(rb0, rb1), pk2(rb2, rb3)};            \
    }                                                                            \
    asm volatile("s_waitcnt lgkmcnt(0)" ::: "memory");                           \
    __builtin_amdgcn_s_barrier();                                                \
    asm volatile("" ::: "memory");                                               \
    f32x4 acco0 = (f32x4){bf2f((unsigned short)aO[0]), bf2f((unsigned short)aO[1]), \
                          bf2f((unsigned short)aO[2]), bf2f((unsigned short)aO[3])}; \
    f32x4 acco1 = (f32x4){bf2f((unsigned short)aO[4]), bf2f((unsigned short)aO[5]), \
                          bf2f((unsigned short)aO[6]), bf2f((unsigned short)aO[7])}; \
    _Pragma("unroll")                                                            \
    for (int kt = 0; kt < 8; ++kt) {                                             \
      short8 ra = NOREAD ? hreg : *(const short8*)(rrd + kt * 64);               \
      acco0 = mfma16(wbo[0][kt], ra, acco0);                                     \
      acco1 = mfma16(wbo[1][kt], ra, acco1);                                     \
    }                                                                            \
    {                                                                            \
      float u0 = sigmoid_f(accu0[0]), u1 = sigmoid_f(accu0[1]);                  \
      float u2 = sigmoid_f(accu0[2]), u3 = sigmoid_f(accu0[3]);                  \
      float u4 = sigmoid_f(accu1[0]), u5 = sigmoid_f(accu1[1]);                  \
      float u6 = sigmoid_f(accu1[2]), u7 = sigmoid_f(accu1[3]);                  \
      hm0 += u0 * (tanh_f(acco0[0]) - hm0);                                      \
      hm1 += u1 * (tanh_f(acco0[1]) - hm1);                                      \
      hm2 += u2 * (tanh_f(acco0[2]) - hm2);                                      \
      hm3 += u3 * (tanh_f(acco0[3]) - hm3);                                      \
      hm4 += u4 * (tanh_f(acco1[0]) - hm4);                                      \
      hm5 += u5 * (tanh_f(acco1[1]) - hm5);                                      \
      hm6 += u6 * (tanh_f(acco1[2]) - hm6);                                      \
      hm7 += u7 * (tanh_f(acco1[3]) - hm7);                                      \
      *(uint2v*)(hwr0)      = (uint2v){pk2(hm0, hm1), pk2(hm2, hm3)};            \
      *(uint2v*)(hwr0 + 32) = (uint2v){pk2(hm4, hm5), pk2(hm6, hm7)};            \
    }                                                                            \
    asm volatile("s_waitcnt lgkmcnt(0)" ::: "memory");                           \
    __builtin_amdgcn_s_barrier();                                                \
    asm volatile("" ::: "memory");                                               \
  }

  for (int t = 0; t < TT; t += 2) {
    STEP_BODY(t)
    STEP_BODY(t + 1)
  }
#undef STEP_BODY

  const int orow = bblk * 16 + b16;
  const int c0 = cw + q * 4;
  *(f32x4*)(&outp[orow * 256 + c0])      = (f32x4){hm0, hm1, hm2, hm3};
  *(f32x4*)(&outp[orow * 256 + c0 + 16]) = (f32x4){hm4, hm5, hm6, hm7};
}

// real path (== R4 scan) and distinct-named probes
__global__ __launch_bounds__(512, 2) void scan_kernel(
    const float* __restrict__ Whu, const float* __restrict__ Whr,
    const float* __restrict__ Wro, const unsigned short* __restrict__ Ap,
    float* __restrict__ out) {
  scan_body<0, 0>(Whu, Whr, Wro, Ap, out);
}
__global__ __launch_bounds__(512, 2) void probe_noread(
    const float* __restrict__ Whu, const float* __restrict__ Whr,
    const float* __restrict__ Wro, const unsigned short* __restrict__ Ap,
    float* __restrict__ out) {
  scan_body<1, 0>(Whu, Whr, Wro, Ap, out);
}
__global__ __launch_bounds__(512, 2) void probe_noring(
    const float* __restrict__ Whu, const float* __restrict__ Whr,
    const float* __restrict__ Wro, const unsigned short* __restrict__ Ap,
    float* __restrict__ out) {
  scan_body<0, 1>(Whu, Whr, Wro, Ap, out);
}
__global__ __launch_bounds__(512, 2) void probe_skel(
    const float* __restrict__ Whu, const float* __restrict__ Whr,
    const float* __restrict__ Wro, const unsigned short* __restrict__ Ap,
    float* __restrict__ out) {
  scan_body<1, 1>(Whu, Whr, Wro, Ap, out);
}

__global__ void ws_signal_kernel(float* out, float v) {
  out[blockIdx.x * 256 + threadIdx.x] = v;
}

extern "C" void kernel_launch(void* const* d_in, const int* in_sizes, int n_in,
                              void* d_out, int out_size, void* d_ws, size_t ws_size,
                              hipStream_t stream) {
  const float* x   = (const float*)d_in[0];
  const float* Wxu = (const float*)d_in[1];
  const float* Whu = (const float*)d_in[2];
  const float* bu  = (const float*)d_in[3];
  const float* Wxr = (const float*)d_in[4];
  const float* Whr = (const float*)d_in[5];
  const float* br  = (const float*)d_in[6];
  const float* Wxo = (const float*)d_in[7];
  const float* Wro = (const float*)d_in[8];
  const float* bo  = (const float*)d_in[9];
  float* out = (float*)d_out;

  const size_t needed = (size_t)TT * 3 * 4 * 4096 * 2;  // 192 MiB bf16 A'
  if (ws_size < needed) {
    ws_signal_kernel<<<64, 256, 0, stream>>>(out, (float)(ws_size >> 20));
    return;
  }
  unsigned short* Ap = (unsigned short*)d_ws;
  // probe outputs: tail of d_ws (proj rewrites all of A' every launch)
  float* vout = (float*)((char*)d_ws + needed - (1u << 20));

  proj_kernel<<<1024, 512, 0, stream>>>(x, Wxu, Wxr, Wxo, bu, br, bo, Ap);
  scan_kernel<<<4, 512, 0, stream>>>(Whu, Whr, Wro, Ap, out);      // REAL output

  probe_noread<<<4, 512, 0, stream>>>(Whu, Whr, Wro, Ap, vout);
  probe_noring<<<4, 512, 0, stream>>>(Whu, Whr, Wro, Ap, vout + 65536);
  probe_skel  <<<4, 512, 0, stream>>>(Whu, Whr, Wro, Ap, vout + 131072);
}

// Round 9
// 3925.608 us; speedup vs baseline: 3.0925x; 3.0925x over previous
//
#include <hip/hip_runtime.h>

// NewGRU: B=64, T=2048, D=256, U=256
// R9 = R4 scan with MFMA dependency chains split 8-deep -> 2x4-deep (partial
// accumulators merged by one add), u-sigmoid deferred into phase-2's r-read
// latency shadow, and s_setprio(1) around the MFMA clusters.  Everything else
// (proj, ring, vmcnt(6), 544B-stride tiles, barriers) verbatim from R4.

#define TT 2048
#define DD 256

typedef __attribute__((ext_vector_type(8))) short short8;          // 8 x bf16 bits
typedef __attribute__((ext_vector_type(4))) unsigned short us4;    // 4 x bf16 bits
typedef __attribute__((ext_vector_type(2))) unsigned int uint2v;   // 8B store
typedef __attribute__((ext_vector_type(4))) float f32x4;

__device__ __forceinline__ unsigned short f2bf(float f) {          // RTN f32->bf16
  unsigned u = __float_as_uint(f);
  return (unsigned short)((u + 0x7FFFu + ((u >> 16) & 1u)) >> 16);
}
__device__ __forceinline__ float bf2f(unsigned short s) {
  return __uint_as_float(((unsigned)s) << 16);
}
__device__ __forceinline__ unsigned pk2(float lo, float hi) {      // 2xbf16 pack
  unsigned a = __float_as_uint(lo) + 0x8000u;
  unsigned b = __float_as_uint(hi) + 0x8000u;
  return (b & 0xFFFF0000u) | (a >> 16);
}
__device__ __forceinline__ float sigmoid_f(float x) {
  return __builtin_amdgcn_rcpf(1.f + __builtin_amdgcn_exp2f(x * -1.44269504f));
}
__device__ __forceinline__ float tanh_f(float x) {
  return 1.f - 2.f * __builtin_amdgcn_rcpf(1.f + __builtin_amdgcn_exp2f(x * 2.88539008f));
}
__device__ __forceinline__ f32x4 mfma16(short8 a, short8 b, f32x4 c) {
  return __builtin_amdgcn_mfma_f32_16x16x32_bf16(a, b, c, 0, 0, 0);
}
__device__ __forceinline__ void load_lds16(const void* gp, void* lp) {
  __builtin_amdgcn_global_load_lds((__attribute__((address_space(1))) void*)(gp),
                                   (__attribute__((address_space(3))) void*)(lp),
                                   16, 0, 0);
}
// XOR swizzle used only by proj_kernel's x tile (verified R1).
__device__ __forceinline__ unsigned swz(unsigned row, unsigned byteInRow) {
  return row * 512u + (byteInRow ^ ((row & 7u) << 4));
}

// ---------------------------------------------------------------------------
// proj_kernel: VERBATIM R4 (verified).
// ---------------------------------------------------------------------------
__global__ __launch_bounds__(512) void proj_kernel(
    const float* __restrict__ x,
    const float* __restrict__ Wxu, const float* __restrict__ Wxr,
    const float* __restrict__ Wxo,
    const float* __restrict__ bu, const float* __restrict__ br,
    const float* __restrict__ bo,
    unsigned short* __restrict__ Ap)
{
  __shared__ alignas(16) unsigned short x_lds[16 * 256];

  const int tid = threadIdx.x;
  const int w = tid >> 6, l = tid & 63;
  const int q = l >> 4, b16 = l & 15;
  const int bblk = blockIdx.x & 3;
  const int tc = blockIdx.x >> 2;
  const int b0 = bblk * 16;

  short8 wx[6][8];
  f32x4 bbv[6];
#pragma unroll
  for (int n = 0; n < 6; ++n) {
    int ntg = w * 6 + n;
    const float* Wg = (ntg < 16) ? Wxu : (ntg < 32) ? Wxr : Wxo;
    const float* bg = (ntg < 16) ? bu : (ntg < 32) ? br : bo;
    int ct = ntg & 15;
    int col = ct * 16 + b16;
    int c0 = ct * 16 + q * 4;
    bbv[n] = (f32x4){bg[c0], bg[c0 + 1], bg[c0 + 2], bg[c0 + 3]};
#pragma unroll
    for (int kt = 0; kt < 8; ++kt) {
      int k0 = kt * 32 + q * 8;
      short8 f;
#pragma unroll
      for (int j = 0; j < 8; ++j) f[j] = (short)f2bf(Wg[(k0 + j) * 256 + col]);
      wx[n][kt] = f;
    }
  }

  for (int it = 0; it < 8; ++it) {
    const int t = tc * 8 + it;
    {
      int row = tid >> 5;
      int part = tid & 31;
      const float* src = x + (((size_t)(b0 + row) * TT + t) * DD) + part * 8;
      float4 f0 = *(const float4*)(src);
      float4 f1 = *(const float4*)(src + 4);
      us4 s0 = { f2bf(f0.x), f2bf(f0.y), f2bf(f0.z), f2bf(f0.w) };
      us4 s1 = { f2bf(f1.x), f2bf(f1.y), f2bf(f1.z), f2bf(f1.w) };
      unsigned base = swz((unsigned)row, (unsigned)(part * 16));
      *(us4*)((char*)x_lds + base) = s0;
      *(us4*)((char*)x_lds + base + 8) = s1;
    }
    __syncthreads();

    f32x4 acc[6];
#pragma unroll
    for (int n = 0; n < 6; ++n) acc[n] = bbv[n];
#pragma unroll
    for (int kt = 0; kt < 8; ++kt) {
      short8 xa = *(const short8*)((const char*)x_lds + swz(b16, kt * 64 + q * 16));
#pragma unroll
      for (int n = 0; n < 6; ++n) acc[n] = mfma16(wx[n][kt], xa, acc[n]);
    }
    __syncthreads();

#pragma unroll
    for (int n = 0; n < 6; ++n) {
      int ntg = w * 6 + n;
      int g = ntg >> 4, ct = ntg & 15;
      us4 st = { f2bf(acc[n][0]), f2bf(acc[n][1]), f2bf(acc[n][2]), f2bf(acc[n][3]) };
      size_t base = (((size_t)t * 3 + g) * 4 + bblk) * 4096
                    + (ct >> 1) * 512 + l * 8 + (ct & 1) * 4;
      *(us4*)(Ap + base) = st;
    }
  }
}

// ---------------------------------------------------------------------------
// scan_kernel: R4 structure; chains split, u-sigmoid deferred, setprio.
// ---------------------------------------------------------------------------
#define RING_SLOT 24576
#define HOFF 98304
#define ROFF 107008

__global__ __launch_bounds__(512, 2) void scan_kernel(
    const float* __restrict__ Whu, const float* __restrict__ Whr,
    const float* __restrict__ Wro,
    const unsigned short* __restrict__ Ap,
    float* __restrict__ out)
{
  __shared__ alignas(16) char lds8[115712];

  const int tid = threadIdx.x;
  const int w = tid >> 6, l = tid & 63;
  const int q = l >> 4, b16 = l & 15;
  const int bblk = blockIdx.x;
  const int cw = w * 32;

  short8 wbu[2][8], wbr[2][8], wbo[2][8];
#pragma unroll
  for (int n = 0; n < 2; ++n) {
    const int col = cw + n * 16 + b16;
#pragma unroll
    for (int kt = 0; kt < 8; ++kt) {
      const int k0 = kt * 32 + q * 8;
      short8 fu, fr, fo;
#pragma unroll
      for (int j = 0; j < 8; ++j) {
        fu[j] = (short)f2bf(Whu[(k0 + j) * 256 + col]);
        fr[j] = (short)f2bf(Whr[(k0 + j) * 256 + col]);
        fo[j] = (short)f2bf(Wro[(k0 + j) * 256 + col]);
      }
      wbu[n][kt] = fu; wbr[n][kt] = fr; wbo[n][kt] = fo;
    }
  }

  const unsigned rowb = (unsigned)(b16 * 544);
  const char* hrd = lds8 + HOFF + rowb + q * 16;           // + kt*64 (imm)
  const char* rrd = lds8 + ROFF + rowb + q * 16;
  char* hwr0 = lds8 + HOFF + rowb + (cw + q * 4) * 2;      // 8B; second at +32
  char* rwr0 = lds8 + ROFF + rowb + (cw + q * 4) * 2;
  const char* ringr = lds8 + w * 1024 + l * 16;            // + slot*24576 + g*8192

  const unsigned short* apl = Ap + (size_t)bblk * 4096 + w * 512 + l * 8;

  for (int i = tid; i < 8704 / 4; i += 512) *(int*)(lds8 + HOFF + i * 4) = 0;

  float hm0 = 0, hm1 = 0, hm2 = 0, hm3 = 0, hm4 = 0, hm5 = 0, hm6 = 0, hm7 = 0;

#pragma unroll
  for (int t0 = 0; t0 < 3; ++t0) {
    const unsigned short* s = apl + (size_t)t0 * 49152u;
    char* d = lds8 + (t0 & 3) * RING_SLOT + w * 1024;
    load_lds16(s,         d);
    load_lds16(s + 16384, d + 8192);
    load_lds16(s + 32768, d + 16384);
  }
  __syncthreads();

#define STEP_BODY(T)                                                             \
  {                                                                              \
    asm volatile("s_waitcnt vmcnt(6)" ::: "memory");                             \
    { /* prefetch step T+3 (clamped) */                                          \
      int tp = (T) + 3; if (tp > TT - 1) tp = TT - 1;                            \
      const unsigned short* s = apl + (size_t)tp * 49152u;                       \
      char* d = lds8 + (tp & 3) * RING_SLOT + w * 1024;                          \
      load_lds16(s,         d);                                                  \
      load_lds16(s + 16384, d + 8192);                                           \
      load_lds16(s + 32768, d + 16384);                                          \
    }                                                                            \
    const char* rp = ringr + ((T) & 3) * RING_SLOT;                              \
    short8 aU = *(const short8*)(rp);                                            \
    short8 aR = *(const short8*)(rp + 8192);                                     \
    short8 aO = *(const short8*)(rp + 16384);   /* stash for phase 2 */          \
    /* ---- phase 1: split-chain MFMA (depth 4 + depth 4) ---- */                \
    f32x4 accu0a = (f32x4){bf2f((unsigned short)aU[0]), bf2f((unsigned short)aU[1]), \
                           bf2f((unsigned short)aU[2]), bf2f((unsigned short)aU[3])}; \
    f32x4 accu1a = (f32x4){bf2f((unsigned short)aU[4]), bf2f((unsigned short)aU[5]), \
                           bf2f((unsigned short)aU[6]), bf2f((unsigned short)aU[7])}; \
    f32x4 accr0a = (f32x4){bf2f((unsigned short)aR[0]), bf2f((unsigned short)aR[1]), \
                           bf2f((unsigned short)aR[2]), bf2f((unsigned short)aR[3])}; \
    f32x4 accr1a = (f32x4){bf2f((unsigned short)aR[4]), bf2f((unsigned short)aR[5]), \
                           bf2f((unsigned short)aR[6]), bf2f((unsigned short)aR[7])}; \
    f32x4 accu0b = (f32x4){0.f, 0.f, 0.f, 0.f};                                  \
    f32x4 accu1b = (f32x4){0.f, 0.f, 0.f, 0.f};                                  \
    f32x4 accr0b = (f32x4){0.f, 0.f, 0.f, 0.f};                                  \
    f32x4 accr1b = (f32x4){0.f, 0.f, 0.f, 0.f};                                  \
    __builtin_amdgcn_s_setprio(1);                                               \
    _Pragma("unroll")                                                            \
    for (int kt = 0; kt < 4; ++kt) {                                             \
      short8 ha = *(const short8*)(hrd + kt * 64);                               \
      accr0a = mfma16(wbr[0][kt], ha, accr0a);                                   \
      accr1a = mfma16(wbr[1][kt], ha, accr1a);                                   \
      accu0a = mfma16(wbu[0][kt], ha, accu0a);                                   \
      accu1a = mfma16(wbu[1][kt], ha, accu1a);                                   \
    }                                                                            \
    _Pragma("unroll")                                                            \
    for (int kt = 4; kt < 8; ++kt) {                                             \
      short8 ha = *(const short8*)(hrd + kt * 64);                               \
      accr0b = mfma16(wbr[0][kt], ha, accr0b);                                   \
      accr1b = mfma16(wbr[1][kt], ha, accr1b);                                   \
      accu0b = mfma16(wbu[0][kt], ha, accu0b);                                   \
      accu1b = mfma16(wbu[1][kt], ha, accu1b);                                   \
    }                                                                            \
    __builtin_amdgcn_s_setprio(0);                                               \
    f32x4 accr0 = accr0a + accr0b;                                               \
    f32x4 accr1 = accr1a + accr1b;                                               \
    f32x4 accu0 = accu0a + accu0b;   /* sigmoid deferred to phase 2 */           \
    f32x4 accu1 = accu1a + accu1b;                                               \
    { /* r = sigmoid, pack, write */                                             \
      float ra0 = sigmoid_f(accr0[0]), ra1 = sigmoid_f(accr0[1]);                \
      float ra2 = sigmoid_f(accr0[2]), ra3 = sigmoid_f(accr0[3]);                \
      float rb0 = sigmoid_f(accr1[0]), rb1 = sigmoid_f(accr1[1]);                \
      float rb2 = sigmoid_f(accr1[2]), rb3 = sigmoid_f(accr1[3]);                \
      *(uint2v*)(rwr0)      = (uint2v){pk2(ra0, ra1), pk2(ra2, ra3)};            \
      *(uint2v*)(rwr0 + 32) = (uint2v){pk2(rb0, rb1), pk2(rb2, rb3)};            \
    }                                                                            \
    asm volatile("s_waitcnt lgkmcnt(0)" ::: "memory");                           \
    __builtin_amdgcn_s_barrier();                                                \
    asm volatile("" ::: "memory");                                               \
    /* ---- phase 2 ---- */                                                      \
    f32x4 acco0a = (f32x4){bf2f((unsigned short)aO[0]), bf2f((unsigned short)aO[1]), \
                           bf2f((unsigned short)aO[2]), bf2f((unsigned short)aO[3])}; \
    f32x4 acco1a = (f32x4){bf2f((unsigned short)aO[4]), bf2f((unsigned short)aO[5]), \
                           bf2f((unsigned short)aO[6]), bf2f((unsigned short)aO[7])}; \
    f32x4 acco0b = (f32x4){0.f, 0.f, 0.f, 0.f};                                  \
    f32x4 acco1b = (f32x4){0.f, 0.f, 0.f, 0.f};                                  \
    /* u sigmoids here: fill the r-read latency shadow */                        \
    float u0 = sigmoid_f(accu0[0]), u1 = sigmoid_f(accu0[1]);                    \
    float u2 = sigmoid_f(accu0[2]), u3 = sigmoid_f(accu0[3]);                    \
    float u4 = sigmoid_f(accu1[0]), u5 = sigmoid_f(accu1[1]);                    \
    float u6 = sigmoid_f(accu1[2]), u7 = sigmoid_f(accu1[3]);                    \
    __builtin_amdgcn_s_setprio(1);                                               \
    _Pragma("unroll")                                                            \
    for (int kt = 0; kt < 4; ++kt) {                                             \
      short8 ra = *(const short8*)(rrd + kt * 64);                               \
      acco0a = mfma16(wbo[0][kt], ra, acco0a);                                   \
      acco1a = mfma16(wbo[1][kt], ra, acco1a);                                   \
    }                                                                            \
    _Pragma("unroll")                                                            \
    for (int kt = 4; kt < 8; ++kt) {                                             \
      short8 ra = *(const short8*)(rrd + kt * 64);                               \
      acco0b = mfma16(wbo[0][kt], ra, acco0b);                                   \
      acco1b = mfma16(wbo[1][kt], ra, acco1b);                                   \
    }                                                                            \
    __builtin_amdgcn_s_setprio(0);                                               \
    f32x4 acco0 = acco0a + acco0b;                                               \
    f32x4 acco1 = acco1a + acco1b;                                               \
    {                                                                            \
      hm0 += u0 * (tanh_f(acco0[0]) - hm0);                                      \
      hm1 += u1 * (tanh_f(acco0[1]) - hm1);                                      \
      hm2 += u2 * (tanh_f(acco0[2]) - hm2);                                      \
      hm3 += u3 * (tanh_f(acco0[3]) - hm3);                                      \
      hm4 += u4 * (tanh_f(acco1[0]) - hm4);                                      \
      hm5 += u5 * (tanh_f(acco1[1]) - hm5);                                      \
      hm6 += u6 * (tanh_f(acco1[2]) - hm6);                                      \
      hm7 += u7 * (tanh_f(acco1[3]) - hm7);                                      \
      *(uint2v*)(hwr0)      = (uint2v){pk2(hm0, hm1), pk2(hm2, hm3)};            \
      *(uint2v*)(hwr0 + 32) = (uint2v){pk2(hm4, hm5), pk2(hm6, hm7)};            \
    }                                                                            \
    asm volatile("s_waitcnt lgkmcnt(0)" ::: "memory");                           \
    __builtin_amdgcn_s_barrier();                                                \
    asm volatile("" ::: "memory");                                               \
  }

  for (int t = 0; t < TT; t += 2) {
    STEP_BODY(t)
    STEP_BODY(t + 1)
  }
#undef STEP_BODY

  const int orow = bblk * 16 + b16;
  const int c0 = cw + q * 4;
  *(f32x4*)(&out[orow * 256 + c0])      = (f32x4){hm0, hm1, hm2, hm3};
  *(f32x4*)(&out[orow * 256 + c0 + 16]) = (f32x4){hm4, hm5, hm6, hm7};
}

__global__ void ws_signal_kernel(float* out, float v) {
  out[blockIdx.x * 256 + threadIdx.x] = v;
}

extern "C" void kernel_launch(void* const* d_in, const int* in_sizes, int n_in,
                              void* d_out, int out_size, void* d_ws, size_t ws_size,
                              hipStream_t stream) {
  const float* x   = (const float*)d_in[0];
  const float* Wxu = (const float*)d_in[1];
  const float* Whu = (const float*)d_in[2];
  const float* bu  = (const float*)d_in[3];
  const float* Wxr = (const float*)d_in[4];
  const float* Whr = (const float*)d_in[5];
  const float* br  = (const float*)d_in[6];
  const float* Wxo = (const float*)d_in[7];
  const float* Wro = (const float*)d_in[8];
  const float* bo  = (const float*)d_in[9];
  float* out = (float*)d_out;

  const size_t needed = (size_t)TT * 3 * 4 * 4096 * 2;  // 192 MiB bf16 A'
  if (ws_size < needed) {
    ws_signal_kernel<<<64, 256, 0, stream>>>(out, (float)(ws_size >> 20));
    return;
  }
  unsigned short* Ap = (unsigned short*)d_ws;
  proj_kernel<<<1024, 512, 0, stream>>>(x, Wxu, Wxr, Wxo, bu, br, bo, Ap);
  scan_kernel<<<4, 512, 0, stream>>>(Whu, Whr, Wro, Ap, out);
}

// Round 10
// 3725.969 us; speedup vs baseline: 3.2582x; 1.0536x over previous
//
#include <hip/hip_runtime.h>

// NewGRU: B=64, T=2048, D=256, U=256
// R10 = R4 (3496us scan, verified; R9's chain-split/setprio/defer reverted)
// with two attributable edits:
//   1. bf16 packing via v_cvt_pk_bf16_f32 (1 op/pair vs ~5 for pk2 emulation)
//   2. o-gate ring read + unpack moved into phase 2 (balances phase loads;
//      slot (T&3) is live until T+3's prefetch, own-wave slice -> no hazard)

#define TT 2048
#define DD 256

typedef __attribute__((ext_vector_type(8))) short short8;          // 8 x bf16 bits
typedef __attribute__((ext_vector_type(4))) unsigned short us4;    // 4 x bf16 bits
typedef __attribute__((ext_vector_type(2))) unsigned int uint2v;   // 8B store
typedef __attribute__((ext_vector_type(4))) float f32x4;

__device__ __forceinline__ unsigned short f2bf(float f) {          // RTN f32->bf16
  unsigned u = __float_as_uint(f);
  return (unsigned short)((u + 0x7FFFu + ((u >> 16) & 1u)) >> 16);
}
__device__ __forceinline__ float bf2f(unsigned short s) {
  return __uint_as_float(((unsigned)s) << 16);
}
// packed bf16 pair via the HW converter (RNE); plain VALU op, HW-interlocked.
__device__ __forceinline__ unsigned cvtpk(float lo, float hi) {
  unsigned r;
  asm("v_cvt_pk_bf16_f32 %0, %1, %2" : "=v"(r) : "v"(lo), "v"(hi));
  return r;
}
__device__ __forceinline__ float sigmoid_f(float x) {
  return __builtin_amdgcn_rcpf(1.f + __builtin_amdgcn_exp2f(x * -1.44269504f));
}
__device__ __forceinline__ float tanh_f(float x) {
  return 1.f - 2.f * __builtin_amdgcn_rcpf(1.f + __builtin_amdgcn_exp2f(x * 2.88539008f));
}
__device__ __forceinline__ f32x4 mfma16(short8 a, short8 b, f32x4 c) {
  return __builtin_amdgcn_mfma_f32_16x16x32_bf16(a, b, c, 0, 0, 0);
}
__device__ __forceinline__ void load_lds16(const void* gp, void* lp) {
  __builtin_amdgcn_global_load_lds((__attribute__((address_space(1))) void*)(gp),
                                   (__attribute__((address_space(3))) void*)(lp),
                                   16, 0, 0);
}
// XOR swizzle used only by proj_kernel's x tile (verified R1).
__device__ __forceinline__ unsigned swz(unsigned row, unsigned byteInRow) {
  return row * 512u + (byteInRow ^ ((row & 7u) << 4));
}

// ---------------------------------------------------------------------------
// proj_kernel: VERBATIM R4 (verified).
// ---------------------------------------------------------------------------
__global__ __launch_bounds__(512) void proj_kernel(
    const float* __restrict__ x,
    const float* __restrict__ Wxu, const float* __restrict__ Wxr,
    const float* __restrict__ Wxo,
    const float* __restrict__ bu, const float* __restrict__ br,
    const float* __restrict__ bo,
    unsigned short* __restrict__ Ap)
{
  __shared__ alignas(16) unsigned short x_lds[16 * 256];

  const int tid = threadIdx.x;
  const int w = tid >> 6, l = tid & 63;
  const int q = l >> 4, b16 = l & 15;
  const int bblk = blockIdx.x & 3;
  const int tc = blockIdx.x >> 2;
  const int b0 = bblk * 16;

  short8 wx[6][8];
  f32x4 bbv[6];
#pragma unroll
  for (int n = 0; n < 6; ++n) {
    int ntg = w * 6 + n;
    const float* Wg = (ntg < 16) ? Wxu : (ntg < 32) ? Wxr : Wxo;
    const float* bg = (ntg < 16) ? bu : (ntg < 32) ? br : bo;
    int ct = ntg & 15;
    int col = ct * 16 + b16;
    int c0 = ct * 16 + q * 4;
    bbv[n] = (f32x4){bg[c0], bg[c0 + 1], bg[c0 + 2], bg[c0 + 3]};
#pragma unroll
    for (int kt = 0; kt < 8; ++kt) {
      int k0 = kt * 32 + q * 8;
      short8 f;
#pragma unroll
      for (int j = 0; j < 8; ++j) f[j] = (short)f2bf(Wg[(k0 + j) * 256 + col]);
      wx[n][kt] = f;
    }
  }

  for (int it = 0; it < 8; ++it) {
    const int t = tc * 8 + it;
    {
      int row = tid >> 5;
      int part = tid & 31;
      const float* src = x + (((size_t)(b0 + row) * TT + t) * DD) + part * 8;
      float4 f0 = *(const float4*)(src);
      float4 f1 = *(const float4*)(src + 4);
      us4 s0 = { f2bf(f0.x), f2bf(f0.y), f2bf(f0.z), f2bf(f0.w) };
      us4 s1 = { f2bf(f1.x), f2bf(f1.y), f2bf(f1.z), f2bf(f1.w) };
      unsigned base = swz((unsigned)row, (unsigned)(part * 16));
      *(us4*)((char*)x_lds + base) = s0;
      *(us4*)((char*)x_lds + base + 8) = s1;
    }
    __syncthreads();

    f32x4 acc[6];
#pragma unroll
    for (int n = 0; n < 6; ++n) acc[n] = bbv[n];
#pragma unroll
    for (int kt = 0; kt < 8; ++kt) {
      short8 xa = *(const short8*)((const char*)x_lds + swz(b16, kt * 64 + q * 16));
#pragma unroll
      for (int n = 0; n < 6; ++n) acc[n] = mfma16(wx[n][kt], xa, acc[n]);
    }
    __syncthreads();

#pragma unroll
    for (int n = 0; n < 6; ++n) {
      int ntg = w * 6 + n;
      int g = ntg >> 4, ct = ntg & 15;
      us4 st = { f2bf(acc[n][0]), f2bf(acc[n][1]), f2bf(acc[n][2]), f2bf(acc[n][3]) };
      size_t base = (((size_t)t * 3 + g) * 4 + bblk) * 4096
                    + (ct >> 1) * 512 + l * 8 + (ct & 1) * 4;
      *(us4*)(Ap + base) = st;
    }
  }
}

// ---------------------------------------------------------------------------
// scan_kernel: R4 structure; cvt_pk packing; o-gate read in phase 2.
// ---------------------------------------------------------------------------
#define RING_SLOT 24576
#define HOFF 98304
#define ROFF 107008

__global__ __launch_bounds__(512, 2) void scan_kernel(
    const float* __restrict__ Whu, const float* __restrict__ Whr,
    const float* __restrict__ Wro,
    const unsigned short* __restrict__ Ap,
    float* __restrict__ out)
{
  __shared__ alignas(16) char lds8[115712];

  const int tid = threadIdx.x;
  const int w = tid >> 6, l = tid & 63;
  const int q = l >> 4, b16 = l & 15;
  const int bblk = blockIdx.x;
  const int cw = w * 32;

  short8 wbu[2][8], wbr[2][8], wbo[2][8];
#pragma unroll
  for (int n = 0; n < 2; ++n) {
    const int col = cw + n * 16 + b16;
#pragma unroll
    for (int kt = 0; kt < 8; ++kt) {
      const int k0 = kt * 32 + q * 8;
      short8 fu, fr, fo;
#pragma unroll
      for (int j = 0; j < 8; ++j) {
        fu[j] = (short)f2bf(Whu[(k0 + j) * 256 + col]);
        fr[j] = (short)f2bf(Whr[(k0 + j) * 256 + col]);
        fo[j] = (short)f2bf(Wro[(k0 + j) * 256 + col]);
      }
      wbu[n][kt] = fu; wbr[n][kt] = fr; wbo[n][kt] = fo;
    }
  }

  const unsigned rowb = (unsigned)(b16 * 544);
  const char* hrd = lds8 + HOFF + rowb + q * 16;           // + kt*64 (imm)
  const char* rrd = lds8 + ROFF + rowb + q * 16;
  char* hwr0 = lds8 + HOFF + rowb + (cw + q * 4) * 2;      // 8B; second at +32
  char* rwr0 = lds8 + ROFF + rowb + (cw + q * 4) * 2;
  const char* ringr = lds8 + w * 1024 + l * 16;            // + slot*24576 + g*8192

  const unsigned short* apl = Ap + (size_t)bblk * 4096 + w * 512 + l * 8;

  for (int i = tid; i < 8704 / 4; i += 512) *(int*)(lds8 + HOFF + i * 4) = 0;

  float hm0 = 0, hm1 = 0, hm2 = 0, hm3 = 0, hm4 = 0, hm5 = 0, hm6 = 0, hm7 = 0;

#pragma unroll
  for (int t0 = 0; t0 < 3; ++t0) {
    const unsigned short* s = apl + (size_t)t0 * 49152u;
    char* d = lds8 + (t0 & 3) * RING_SLOT + w * 1024;
    load_lds16(s,         d);
    load_lds16(s + 16384, d + 8192);
    load_lds16(s + 32768, d + 16384);
  }
  __syncthreads();

#define STEP_BODY(T)                                                             \
  {                                                                              \
    asm volatile("s_waitcnt vmcnt(6)" ::: "memory");                             \
    { /* prefetch step T+3 (clamped; duplicate loads write identical bytes) */   \
      int tp = (T) + 3; if (tp > TT - 1) tp = TT - 1;                            \
      const unsigned short* s = apl + (size_t)tp * 49152u;                       \
      char* d = lds8 + (tp & 3) * RING_SLOT + w * 1024;                          \
      load_lds16(s,         d);                                                  \
      load_lds16(s + 16384, d + 8192);                                           \
      load_lds16(s + 32768, d + 16384);                                          \
    }                                                                            \
    const char* rp = ringr + ((T) & 3) * RING_SLOT;                              \
    short8 aU = *(const short8*)(rp);                                            \
    short8 aR = *(const short8*)(rp + 8192);                                     \
    f32x4 accu0 = (f32x4){bf2f((unsigned short)aU[0]), bf2f((unsigned short)aU[1]), \
                          bf2f((unsigned short)aU[2]), bf2f((unsigned short)aU[3])}; \
    f32x4 accu1 = (f32x4){bf2f((unsigned short)aU[4]), bf2f((unsigned short)aU[5]), \
                          bf2f((unsigned short)aU[6]), bf2f((unsigned short)aU[7])}; \
    f32x4 accr0 = (f32x4){bf2f((unsigned short)aR[0]), bf2f((unsigned short)aR[1]), \
                          bf2f((unsigned short)aR[2]), bf2f((unsigned short)aR[3])}; \
    f32x4 accr1 = (f32x4){bf2f((unsigned short)aR[4]), bf2f((unsigned short)aR[5]), \
                          bf2f((unsigned short)aR[6]), bf2f((unsigned short)aR[7])}; \
    _Pragma("unroll")                                                            \
    for (int kt = 0; kt < 8; ++kt) {                                             \
      short8 ha = *(const short8*)(hrd + kt * 64);                               \
      accr0 = mfma16(wbr[0][kt], ha, accr0);                                     \
      accr1 = mfma16(wbr[1][kt], ha, accr1);                                     \
      accu0 = mfma16(wbu[0][kt], ha, accu0);                                     \
      accu1 = mfma16(wbu[1][kt], ha, accu1);                                     \
    }                                                                            \
    { /* r = sigmoid, cvt_pk pack, write */                                      \
      float ra0 = sigmoid_f(accr0[0]), ra1 = sigmoid_f(accr0[1]);                \
      float ra2 = sigmoid_f(accr0[2]), ra3 = sigmoid_f(accr0[3]);                \
      float rb0 = sigmoid_f(accr1[0]), rb1 = sigmoid_f(accr1[1]);                \
      float rb2 = sigmoid_f(accr1[2]), rb3 = sigmoid_f(accr1[3]);                \
      *(uint2v*)(rwr0)      = (uint2v){cvtpk(ra0, ra1), cvtpk(ra2, ra3)};        \
      *(uint2v*)(rwr0 + 32) = (uint2v){cvtpk(rb0, rb1), cvtpk(rb2, rb3)};        \
    }                                                                            \
    asm volatile("s_waitcnt lgkmcnt(0)" ::: "memory");                           \
    __builtin_amdgcn_s_barrier();                                                \
    asm volatile("" ::: "memory");                                               \
    /* ---- phase 2: o-gate ring read HERE (slot still live; own slice) ---- */  \
    short8 aO = *(const short8*)(rp + 16384);                                    \
    f32x4 acco0 = (f32x4){bf2f((unsigned short)aO[0]), bf2f((unsigned short)aO[1]), \
                          bf2f((unsigned short)aO[2]), bf2f((unsigned short)aO[3])}; \
    f32x4 acco1 = (f32x4){bf2f((unsigned short)aO[4]), bf2f((unsigned short)aO[5]), \
                          bf2f((unsigned short)aO[6]), bf2f((unsigned short)aO[7])}; \
    _Pragma("unroll")                                                            \
    for (int kt = 0; kt < 8; ++kt) {                                             \
      short8 ra = *(const short8*)(rrd + kt * 64);                               \
      acco0 = mfma16(wbo[0][kt], ra, acco0);                                     \
      acco1 = mfma16(wbo[1][kt], ra, acco1);                                     \
    }                                                                            \
    {                                                                            \
      float u0 = sigmoid_f(accu0[0]), u1 = sigmoid_f(accu0[1]);                  \
      float u2 = sigmoid_f(accu0[2]), u3 = sigmoid_f(accu0[3]);                  \
      float u4 = sigmoid_f(accu1[0]), u5 = sigmoid_f(accu1[1]);                  \
      float u6 = sigmoid_f(accu1[2]), u7 = sigmoid_f(accu1[3]);                  \
      hm0 += u0 * (tanh_f(acco0[0]) - hm0);                                      \
      hm1 += u1 * (tanh_f(acco0[1]) - hm1);                                      \
      hm2 += u2 * (tanh_f(acco0[2]) - hm2);                                      \
      hm3 += u3 * (tanh_f(acco0[3]) - hm3);                                      \
      hm4 += u4 * (tanh_f(acco1[0]) - hm4);                                      \
      hm5 += u5 * (tanh_f(acco1[1]) - hm5);                                      \
      hm6 += u6 * (tanh_f(acco1[2]) - hm6);                                      \
      hm7 += u7 * (tanh_f(acco1[3]) - hm7);                                      \
      *(uint2v*)(hwr0)      = (uint2v){cvtpk(hm0, hm1), cvtpk(hm2, hm3)};        \
      *(uint2v*)(hwr0 + 32) = (uint2v){cvtpk(hm4, hm5), cvtpk(hm6, hm7)};        \
    }                                                                            \
    asm volatile("s_waitcnt lgkmcnt(0)" ::: "memory");                           \
    __builtin_amdgcn_s_barrier();                                                \
    asm volatile("" ::: "memory");                                               \
  }

  for (int t = 0; t < TT; t += 2) {
    STEP_BODY(t)
    STEP_BODY(t + 1)
  }
#undef STEP_BODY

  const int orow = bblk * 16 + b16;
  const int c0 = cw + q * 4;
  *(f32x4*)(&out[orow * 256 + c0])      = (f32x4){hm0, hm1, hm2, hm3};
  *(f32x4*)(&out[orow * 256 + c0 + 16]) = (f32x4){hm4, hm5, hm6, hm7};
}

__global__ void ws_signal_kernel(float* out, float v) {
  out[blockIdx.x * 256 + threadIdx.x] = v;
}

extern "C" void kernel_launch(void* const* d_in, const int* in_sizes, int n_in,
                              void* d_out, int out_size, void* d_ws, size_t ws_size,
                              hipStream_t stream) {
  const float* x   = (const float*)d_in[0];
  const float* Wxu = (const float*)d_in[1];
  const float* Whu = (const float*)d_in[2];
  const float* bu  = (const float*)d_in[3];
  const float* Wxr = (const float*)d_in[4];
  const float* Whr = (const float*)d_in[5];
  const float* br  = (const float*)d_in[6];
  const float* Wxo = (const float*)d_in[7];
  const float* Wro = (const float*)d_in[8];
  const float* bo  = (const float*)d_in[9];
  float* out = (float*)d_out;

  const size_t needed = (size_t)TT * 3 * 4 * 4096 * 2;  // 192 MiB bf16 A'
  if (ws_size < needed) {
    ws_signal_kernel<<<64, 256, 0, stream>>>(out, (float)(ws_size >> 20));
    return;
  }
  unsigned short* Ap = (unsigned short*)d_ws;
  proj_kernel<<<1024, 512, 0, stream>>>(x, Wxu, Wxr, Wxo, bu, br, bo, Ap);
  scan_kernel<<<4, 512, 0, stream>>>(Whu, Whr, Wro, Ap, out);
}

// Round 11
// 3567.022 us; speedup vs baseline: 3.4034x; 1.0446x over previous
//
#include <hip/hip_runtime.h>

// NewGRU: B=64, T=2048, D=256, U=256
// R11 = R10 (3367us scan) + two edits:
//   1. weight/bias pre-scaling: u/r sets x -1.4427 (=-log2 e), o set x +2.8854
//      -> sigmoid = rcp(1+exp2(acc)), tanh = fma(-2, rcp(1+exp2(acc)), 1);
//      deletes the input mul in all 24 activations/thread/step.
//   2. 4-deep unroll: ring slot offsets become compile-time constants.

#define TT 2048
#define DD 256

typedef __attribute__((ext_vector_type(8))) short short8;          // 8 x bf16 bits
typedef __attribute__((ext_vector_type(4))) unsigned short us4;    // 4 x bf16 bits
typedef __attribute__((ext_vector_type(2))) unsigned int uint2v;   // 8B store
typedef __attribute__((ext_vector_type(4))) float f32x4;

__device__ __forceinline__ unsigned short f2bf(float f) {          // RTN f32->bf16
  unsigned u = __float_as_uint(f);
  return (unsigned short)((u + 0x7FFFu + ((u >> 16) & 1u)) >> 16);
}
__device__ __forceinline__ float bf2f(unsigned short s) {
  return __uint_as_float(((unsigned)s) << 16);
}
// packed bf16 pair via the HW converter (RNE); plain VALU op (verified R10).
__device__ __forceinline__ unsigned cvtpk(float lo, float hi) {
  unsigned r;
  asm("v_cvt_pk_bf16_f32 %0, %1, %2" : "=v"(r) : "v"(lo), "v"(hi));
  return r;
}
// pre-scaled activations: input already multiplied by -log2e (u/r) or +2log2e (o)
__device__ __forceinline__ float sigp(float x) {   // sigmoid(orig) given x=-1.4427*orig
  return __builtin_amdgcn_rcpf(1.f + __builtin_amdgcn_exp2f(x));
}
__device__ __forceinline__ float tanhp(float x) {  // tanh(orig) given x=+2.8854*orig
  return __builtin_fmaf(-2.f, __builtin_amdgcn_rcpf(1.f + __builtin_amdgcn_exp2f(x)), 1.f);
}
__device__ __forceinline__ f32x4 mfma16(short8 a, short8 b, f32x4 c) {
  return __builtin_amdgcn_mfma_f32_16x16x32_bf16(a, b, c, 0, 0, 0);
}
__device__ __forceinline__ void load_lds16(const void* gp, void* lp) {
  __builtin_amdgcn_global_load_lds((__attribute__((address_space(1))) void*)(gp),
                                   (__attribute__((address_space(3))) void*)(lp),
                                   16, 0, 0);
}
// XOR swizzle used only by proj_kernel's x tile (verified R1).
__device__ __forceinline__ unsigned swz(unsigned row, unsigned byteInRow) {
  return row * 512u + (byteInRow ^ ((row & 7u) << 4));
}

#define SC_UR (-1.44269504f)
#define SC_O  ( 2.88539008f)

// ---------------------------------------------------------------------------
// proj_kernel: R4 structure; weight/bias scaled per gate (u,r: -1.4427; o: +2.8854).
// ---------------------------------------------------------------------------
__global__ __launch_bounds__(512) void proj_kernel(
    const float* __restrict__ x,
    const float* __restrict__ Wxu, const float* __restrict__ Wxr,
    const float* __restrict__ Wxo,
    const float* __restrict__ bu, const float* __restrict__ br,
    const float* __restrict__ bo,
    unsigned short* __restrict__ Ap)
{
  __shared__ alignas(16) unsigned short x_lds[16 * 256];

  const int tid = threadIdx.x;
  const int w = tid >> 6, l = tid & 63;
  const int q = l >> 4, b16 = l & 15;
  const int bblk = blockIdx.x & 3;
  const int tc = blockIdx.x >> 2;
  const int b0 = bblk * 16;

  short8 wx[6][8];
  f32x4 bbv[6];
#pragma unroll
  for (int n = 0; n < 6; ++n) {
    int ntg = w * 6 + n;
    const float* Wg = (ntg < 16) ? Wxu : (ntg < 32) ? Wxr : Wxo;
    const float* bg = (ntg < 16) ? bu : (ntg < 32) ? br : bo;
    const float sc = (ntg < 32) ? SC_UR : SC_O;
    int ct = ntg & 15;
    int col = ct * 16 + b16;
    int c0 = ct * 16 + q * 4;
    bbv[n] = (f32x4){bg[c0] * sc, bg[c0 + 1] * sc, bg[c0 + 2] * sc, bg[c0 + 3] * sc};
#pragma unroll
    for (int kt = 0; kt < 8; ++kt) {
      int k0 = kt * 32 + q * 8;
      short8 f;
#pragma unroll
      for (int j = 0; j < 8; ++j) f[j] = (short)f2bf(Wg[(k0 + j) * 256 + col] * sc);
      wx[n][kt] = f;
    }
  }

  for (int it = 0; it < 8; ++it) {
    const int t = tc * 8 + it;
    {
      int row = tid >> 5;
      int part = tid & 31;
      const float* src = x + (((size_t)(b0 + row) * TT + t) * DD) + part * 8;
      float4 f0 = *(const float4*)(src);
      float4 f1 = *(const float4*)(src + 4);
      us4 s0 = { f2bf(f0.x), f2bf(f0.y), f2bf(f0.z), f2bf(f0.w) };
      us4 s1 = { f2bf(f1.x), f2bf(f1.y), f2bf(f1.z), f2bf(f1.w) };
      unsigned base = swz((unsigned)row, (unsigned)(part * 16));
      *(us4*)((char*)x_lds + base) = s0;
      *(us4*)((char*)x_lds + base + 8) = s1;
    }
    __syncthreads();

    f32x4 acc[6];
#pragma unroll
    for (int n = 0; n < 6; ++n) acc[n] = bbv[n];
#pragma unroll
    for (int kt = 0; kt < 8; ++kt) {
      short8 xa = *(const short8*)((const char*)x_lds + swz(b16, kt * 64 + q * 16));
#pragma unroll
      for (int n = 0; n < 6; ++n) acc[n] = mfma16(wx[n][kt], xa, acc[n]);
    }
    __syncthreads();

#pragma unroll
    for (int n = 0; n < 6; ++n) {
      int ntg = w * 6 + n;
      int g = ntg >> 4, ct = ntg & 15;
      us4 st = { f2bf(acc[n][0]), f2bf(acc[n][1]), f2bf(acc[n][2]), f2bf(acc[n][3]) };
      size_t base = (((size_t)t * 3 + g) * 4 + bblk) * 4096
                    + (ct >> 1) * 512 + l * 8 + (ct & 1) * 4;
      *(us4*)(Ap + base) = st;
    }
  }
}

// ---------------------------------------------------------------------------
// scan_kernel: R10 structure; scaled weights; pre-scaled activations; 4-deep
// unroll with compile-time ring slots.
// ---------------------------------------------------------------------------
#define RING_SLOT 24576
#define HOFF 98304
#define ROFF 107008

__global__ __launch_bounds__(512, 2) void scan_kernel(
    const float* __restrict__ Whu, const float* __restrict__ Whr,
    const float* __restrict__ Wro,
    const unsigned short* __restrict__ Ap,
    float* __restrict__ out)
{
  __shared__ alignas(16) char lds8[115712];

  const int tid = threadIdx.x;
  const int w = tid >> 6, l = tid & 63;
  const int q = l >> 4, b16 = l & 15;
  const int bblk = blockIdx.x;
  const int cw = w * 32;

  short8 wbu[2][8], wbr[2][8], wbo[2][8];
#pragma unroll
  for (int n = 0; n < 2; ++n) {
    const int col = cw + n * 16 + b16;
#pragma unroll
    for (int kt = 0; kt < 8; ++kt) {
      const int k0 = kt * 32 + q * 8;
      short8 fu, fr, fo;
#pragma unroll
      for (int j = 0; j < 8; ++j) {
        fu[j] = (short)f2bf(Whu[(k0 + j) * 256 + col] * SC_UR);
        fr[j] = (short)f2bf(Whr[(k0 + j) * 256 + col] * SC_UR);
        fo[j] = (short)f2bf(Wro[(k0 + j) * 256 + col] * SC_O);
      }
      wbu[n][kt] = fu; wbr[n][kt] = fr; wbo[n][kt] = fo;
    }
  }

  const unsigned rowb = (unsigned)(b16 * 544);
  const char* hrd = lds8 + HOFF + rowb + q * 16;           // + kt*64 (imm)
  const char* rrd = lds8 + ROFF + rowb + q * 16;
  char* hwr0 = lds8 + HOFF + rowb + (cw + q * 4) * 2;      // 8B; second at +32
  char* rwr0 = lds8 + ROFF + rowb + (cw + q * 4) * 2;
  const char* ringr = lds8 + w * 1024 + l * 16;            // + slot*24576 + g*8192

  const unsigned short* apl = Ap + (size_t)bblk * 4096 + w * 512 + l * 8;

  for (int i = tid; i < 8704 / 4; i += 512) *(int*)(lds8 + HOFF + i * 4) = 0;

  float hm0 = 0, hm1 = 0, hm2 = 0, hm3 = 0, hm4 = 0, hm5 = 0, hm6 = 0, hm7 = 0;

#pragma unroll
  for (int t0 = 0; t0 < 3; ++t0) {
    const unsigned short* s = apl + (size_t)t0 * 49152u;
    char* d = lds8 + (t0 & 3) * RING_SLOT + w * 1024;
    load_lds16(s,         d);
    load_lds16(s + 16384, d + 8192);
    load_lds16(s + 32768, d + 16384);
  }
  __syncthreads();

#define STEP_BODY(T, SLOT, PSLOT)                                                \
  {                                                                              \
    asm volatile("s_waitcnt vmcnt(6)" ::: "memory");                             \
    { /* prefetch step T+3 (clamped; duplicate loads write identical bytes) */   \
      int tp = (T) + 3; if (tp > TT - 1) tp = TT - 1;                            \
      const unsigned short* s = apl + (size_t)tp * 49152u;                       \
      char* d = lds8 + (PSLOT) * RING_SLOT + w * 1024;                           \
      load_lds16(s,         d);                                                  \
      load_lds16(s + 16384, d + 8192);                                           \
      load_lds16(s + 32768, d + 16384);                                          \
    }                                                                            \
    const char* rp = ringr + (SLOT) * RING_SLOT;                                 \
    short8 aU = *(const short8*)(rp);                                            \
    short8 aR = *(const short8*)(rp + 8192);                                     \
    f32x4 accu0 = (f32x4){bf2f((unsigned short)aU[0]), bf2f((unsigned short)aU[1]), \
                          bf2f((unsigned short)aU[2]), bf2f((unsigned short)aU[3])}; \
    f32x4 accu1 = (f32x4){bf2f((unsigned short)aU[4]), bf2f((unsigned short)aU[5]), \
                          bf2f((unsigned short)aU[6]), bf2f((unsigned short)aU[7])}; \
    f32x4 accr0 = (f32x4){bf2f((unsigned short)aR[0]), bf2f((unsigned short)aR[1]), \
                          bf2f((unsigned short)aR[2]), bf2f((unsigned short)aR[3])}; \
    f32x4 accr1 = (f32x4){bf2f((unsigned short)aR[4]), bf2f((unsigned short)aR[5]), \
                          bf2f((unsigned short)aR[6]), bf2f((unsigned short)aR[7])}; \
    _Pragma("unroll")                                                            \
    for (int kt = 0; kt < 8; ++kt) {                                             \
      short8 ha = *(const short8*)(hrd + kt * 64);                               \
      accr0 = mfma16(wbr[0][kt], ha, accr0);                                     \
      accr1 = mfma16(wbr[1][kt], ha, accr1);                                     \
      accu0 = mfma16(wbu[0][kt], ha, accu0);                                     \
      accu1 = mfma16(wbu[1][kt], ha, accu1);                                     \
    }                                                                            \
    { /* r = sigp (pre-scaled), cvt_pk pack, write */                            \
      float ra0 = sigp(accr0[0]), ra1 = sigp(accr0[1]);                          \
      float ra2 = sigp(accr0[2]), ra3 = sigp(accr0[3]);                          \
      float rb0 = sigp(accr1[0]), rb1 = sigp(accr1[1]);                          \
      float rb2 = sigp(accr1[2]), rb3 = sigp(accr1[3]);                          \
      *(uint2v*)(rwr0)      = (uint2v){cvtpk(ra0, ra1), cvtpk(ra2, ra3)};        \
      *(uint2v*)(rwr0 + 32) = (uint2v){cvtpk(rb0, rb1), cvtpk(rb2, rb3)};        \
    }                                                                            \
    asm volatile("s_waitcnt lgkmcnt(0)" ::: "memory");                           \
    __builtin_amdgcn_s_barrier();                                                \
    asm volatile("" ::: "memory");                                               \
    /* ---- phase 2: o-gate ring read here (slot live; own slice) ---- */        \
    short8 aO = *(const short8*)(rp + 16384);                                    \
    f32x4 acco0 = (f32x4){bf2f((unsigned short)aO[0]), bf2f((unsigned short)aO[1]), \
                          bf2f((unsigned short)aO[2]), bf2f((unsigned short)aO[3])}; \
    f32x4 acco1 = (f32x4){bf2f((unsigned short)aO[4]), bf2f((unsigned short)aO[5]), \
                          bf2f((unsigned short)aO[6]), bf2f((unsigned short)aO[7])}; \
    _Pragma("unroll")                                                            \
    for (int kt = 0; kt < 8; ++kt) {                                             \
      short8 ra = *(const short8*)(rrd + kt * 64);                               \
      acco0 = mfma16(wbo[0][kt], ra, acco0);                                     \
      acco1 = mfma16(wbo[1][kt], ra, acco1);                                     \
    }                                                                            \
    {                                                                            \
      float u0 = sigp(accu0[0]), u1 = sigp(accu0[1]);                            \
      float u2 = sigp(accu0[2]), u3 = sigp(accu0[3]);                            \
      float u4 = sigp(accu1[0]), u5 = sigp(accu1[1]);                            \
      float u6 = sigp(accu1[2]), u7 = sigp(accu1[3]);                            \
      hm0 += u0 * (tanhp(acco0[0]) - hm0);                                       \
      hm1 += u1 * (tanhp(acco0[1]) - hm1);                                       \
      hm2 += u2 * (tanhp(acco0[2]) - hm2);                                       \
      hm3 += u3 * (tanhp(acco0[3]) - hm3);                                       \
      hm4 += u4 * (tanhp(acco1[0]) - hm4);                                       \
      hm5 += u5 * (tanhp(acco1[1]) - hm5);                                       \
      hm6 += u6 * (tanhp(acco1[2]) - hm6);                                       \
      hm7 += u7 * (tanhp(acco1[3]) - hm7);                                       \
      *(uint2v*)(hwr0)      = (uint2v){cvtpk(hm0, hm1), cvtpk(hm2, hm3)};        \
      *(uint2v*)(hwr0 + 32) = (uint2v){cvtpk(hm4, hm5), cvtpk(hm6, hm7)};        \
    }                                                                            \
    asm volatile("s_waitcnt lgkmcnt(0)" ::: "memory");                           \
    __builtin_amdgcn_s_barrier();                                                \
    asm volatile("" ::: "memory");                                               \
  }

  for (int t = 0; t < TT; t += 4) {
    STEP_BODY(t,     0, 3)
    STEP_BODY(t + 1, 1, 0)
    STEP_BODY(t + 2, 2, 1)
    STEP_BODY(t + 3, 3, 2)
  }
#undef STEP_BODY

  const int orow = bblk * 16 + b16;
  const int c0 = cw + q * 4;
  *(f32x4*)(&out[orow * 256 + c0])      = (f32x4){hm0, hm1, hm2, hm3};
  *(f32x4*)(&out[orow * 256 + c0 + 16]) = (f32x4){hm4, hm5, hm6, hm7};
}

__global__ void ws_signal_kernel(float* out, float v) {
  out[blockIdx.x * 256 + threadIdx.x] = v;
}

extern "C" void kernel_launch(void* const* d_in, const int* in_sizes, int n_in,
                              void* d_out, int out_size, void* d_ws, size_t ws_size,
                              hipStream_t stream) {
  const float* x   = (const float*)d_in[0];
  const float* Wxu = (const float*)d_in[1];
  const float* Whu = (const float*)d_in[2];
  const float* bu  = (const float*)d_in[3];
  const float* Wxr = (const float*)d_in[4];
  const float* Whr = (const float*)d_in[5];
  const float* br  = (const float*)d_in[6];
  const float* Wxo = (const float*)d_in[7];
  const float* Wro = (const float*)d_in[8];
  const float* bo  = (const float*)d_in[9];
  float* out = (float*)d_out;

  const size_t needed = (size_t)TT * 3 * 4 * 4096 * 2;  // 192 MiB bf16 A'
  if (ws_size < needed) {
    ws_signal_kernel<<<64, 256, 0, stream>>>(out, (float)(ws_size >> 20));
    return;
  }
  unsigned short* Ap = (unsigned short*)d_ws;
  proj_kernel<<<1024, 512, 0, stream>>>(x, Wxu, Wxr, Wxo, bu, br, bo, Ap);
  scan_kernel<<<4, 512, 0, stream>>>(Whu, Whr, Wro, Ap, out);
}